// Round 3
// baseline (15.785 us; speedup 1.0000x reference)
//
#include <hip/hip_runtime.h>

// DAGGenome.get_active_mask — reachability from node 0 along left/right edges.
// Reference: N-step scan with scatter-.set (duplicate indices: LAST wins).
// Equivalent fixpoint: R[c] |= R[lp[c]] | R[rp[c]] where
//   lp[c] = max{ i : left[i]==c && 0<=left[i]<N }  (per-channel last parent).
// Output dtype: bool mask -> harness reads d_out as INT32 (0/1).
//
// Single block, 1024 threads, node c owned by thread c/8 (contiguous chunks).
// Setup: concurrent last-wins scatters via LDS atomicMax into lpI/rpI (ints),
// then each thread pulls its 8 (lp,rp) pairs into REGISTERS — sweeps never
// touch them in LDS again. Per sweep, an unresolved node costs <=2 scattered
// LDS byte reads; own reach state lives in a register bitmask (each node has
// exactly one writer). Two sub-passes per barrier interval (monotone updates
// tolerate staleness), termination via a single __syncthreads_or per sweep.
// LDS: 32 KB lpI + 32 KB rpI + 8 KB reach = 72 KB.

#define NN  8192
#define NT  1024
#define PER (NN / NT)   // 8 nodes per thread, contiguous

__global__ __launch_bounds__(NT) void dag_reach_kernel(
    const int* __restrict__ left,
    const int* __restrict__ right,
    int* __restrict__ out)
{
    __shared__ int           lpI[NN];
    __shared__ int           rpI[NN];
    __shared__ unsigned char reach[NN];

    const int tid  = threadIdx.x;
    const int base = tid * PER;

    // ---- init LDS ----
    #pragma unroll
    for (int k = 0; k < PER; ++k) {
        lpI[base + k] = -1;
        rpI[base + k] = -1;
        reach[base + k] = 0;
    }

    // ---- load edges (contiguous 32 B per thread, coalesced across wave) ----
    int lv[PER], rv[PER];
    #pragma unroll
    for (int k = 0; k < PER; ++k) {
        lv[k] = left[base + k];
        rv[k] = right[base + k];
    }

    __syncthreads();

    // ---- last-wins scatter: keep MAX parent index per target, both channels ----
    #pragma unroll
    for (int k = 0; k < PER; ++k) {
        const int i = base + k;
        const int l = lv[k];
        const int r = rv[k];
        if (l >= 0 && l < NN) atomicMax(&lpI[l], i);
        if (r >= 0 && r < NN) atomicMax(&rpI[r], i);
    }

    __syncthreads();

    // ---- pull my nodes' parents into registers; build pend mask ----
    int lp[PER], rp[PER];
    #pragma unroll
    for (int k = 0; k < PER; ++k) {
        lp[k] = lpI[base + k];
        rp[k] = rpI[base + k];
    }

    unsigned pend = 0, rmask = 0;
    #pragma unroll
    for (int k = 0; k < PER; ++k) {
        const int c = base + k;
        if (c == 0) {
            rmask |= 1u;           // node 0 is the root
            reach[0] = 1;
        } else if (lp[k] >= 0 || rp[k] >= 0) {
            pend |= (1u << k);     // parentless nodes are dead forever
        }
    }

    __syncthreads();               // root + zero-init visible to all

    // ---- fixpoint sweeps: 2 sub-passes per barrier interval ----
    for (;;) {
        int mych = 0;
        for (int sp = 0; sp < 2; ++sp) {
            #pragma unroll
            for (int k = 0; k < PER; ++k) {
                if (pend & (1u << k)) {
                    const int a = lp[k];
                    const int b = rp[k];
                    bool r = (a >= 0) && (reach[a] != 0);
                    if (!r) r = (b >= 0) && (reach[b] != 0);
                    if (r) {
                        reach[base + k] = 1;
                        rmask |= (1u << k);
                        pend  &= ~(1u << k);
                        mych = 1;
                    }
                }
            }
        }
        if (!__syncthreads_or(mych)) break;   // barrier + reduction in one
    }

    // ---- output int32 0/1, contiguous 32 B per thread ----
    #pragma unroll
    for (int k = 0; k < PER; ++k) {
        out[base + k] = (int)((rmask >> k) & 1u);
    }
}

extern "C" void kernel_launch(void* const* d_in, const int* in_sizes, int n_in,
                              void* d_out, int out_size, void* d_ws, size_t ws_size,
                              hipStream_t stream) {
    // setup_inputs order: thresholds, rules_left, rules_right, binary_ops, left, right
    const int* left  = (const int*)d_in[4];
    const int* right = (const int*)d_in[5];
    int* out = (int*)d_out;

    dag_reach_kernel<<<1, NT, 0, stream>>>(left, right, out);
}

// Round 4
// 11.624 us; speedup vs baseline: 1.3579x; 1.3579x over previous
//
#include <hip/hip_runtime.h>

// DAGGenome.get_active_mask — reachability from node 0 along left/right edges.
// Reference: N-step scan with scatter-.set (duplicate indices: LAST wins).
// Equivalent fixpoint: R[c] |= R[lp[c]] | R[rp[c]] where
//   lp[c] = max{ i : left[i]==c && 0<=left[i]<N }  (per-channel last parent).
// Output dtype: bool mask -> harness reads d_out as INT32 (0/1).
//
// R4 design (cost model: sweeps x (barrier + scattered LDS reads) dominates):
//  - 512 threads (8 waves): halves barrier cost vs 1024.
//  - 1 barrier/sweep: epoch-indexed flags[e] (pre-zeroed; progress -> plain
//    store 1; post-barrier same-address broadcast read; no reset/reduce).
//  - single sub-pass (R3's double pass doubled LDS traffic -> regression).
//  - pend bitmask + sentinel reach[NN]==0 -> branchless 2 byte-reads per
//    pending node, 0 reads for resolved/parentless nodes.
//  - strided ownership (i = tid + k*NT) -> coalesced global loads/stores;
//    int4 output stores unpacked from reach dwords.

#define NN   8192
#define NT   512
#define PER  (NN / NT)          // 16 nodes per thread, strided
#define SENT NN                 // sentinel: reach[SENT] stays 0 forever
#define MAXE 512                // epoch cap (graph depth << this)

__global__ __launch_bounds__(NT) void dag_reach_kernel(
    const int* __restrict__ left,
    const int* __restrict__ right,
    int* __restrict__ out)
{
    __shared__ int           lpI[NN + 1];
    __shared__ int           rpI[NN + 1];
    __shared__ unsigned char reach[NN + 4];   // +4: sentinel dword
    __shared__ int           flags[MAXE];

    const int tid = threadIdx.x;

    // ---- global loads first (overlap latency with LDS init) ----
    int lv[PER], rv[PER];
    #pragma unroll
    for (int k = 0; k < PER; ++k) {
        const int i = tid + k * NT;
        lv[k] = left[i];
        rv[k] = right[i];
    }

    // ---- init LDS ----
    #pragma unroll
    for (int k = 0; k < PER; ++k) {
        const int i = tid + k * NT;
        lpI[i] = -1;
        rpI[i] = -1;
    }
    int* reach32 = (int*)reach;
    #pragma unroll
    for (int k = 0; k < (NN / 4) / NT; ++k)   // 2048 dwords / 512 thr = 4
        reach32[tid + k * NT] = 0;
    if (tid == 0) {
        reach32[NN / 4] = 0;   // sentinel bytes reach[NN..NN+3]
        lpI[SENT] = -1;
        rpI[SENT] = -1;
    }
    flags[tid] = 0;            // MAXE == NT
    __syncthreads();

    // ---- last-wins scatter: MAX parent index per target, both channels ----
    #pragma unroll
    for (int k = 0; k < PER; ++k) {
        const int i = tid + k * NT;
        const int l = lv[k];
        const int r = rv[k];
        if ((unsigned)l < (unsigned)NN) atomicMax(&lpI[l], i);
        if ((unsigned)r < (unsigned)NN) atomicMax(&rpI[r], i);
    }
    __syncthreads();

    // ---- pull parents into registers (sentinel-mapped); build pend mask ----
    int lp[PER], rp[PER];
    unsigned pend = 0;
    #pragma unroll
    for (int k = 0; k < PER; ++k) {
        const int i = tid + k * NT;
        const int a = lpI[i];
        const int b = rpI[i];
        lp[k] = (a < 0) ? SENT : a;
        rp[k] = (b < 0) ? SENT : b;
        if ((a >= 0 || b >= 0) && i != 0) pend |= (1u << k);  // parentless = dead
    }
    if (tid == 0) reach[0] = 1;   // root
    __syncthreads();

    // ---- fixpoint sweeps: exactly ONE barrier per sweep ----
    for (int e = 0; ; ++e) {
        if (pend) {
            int prog = 0;
            #pragma unroll
            for (int k = 0; k < PER; ++k) {
                if (pend & (1u << k)) {
                    if (reach[lp[k]] | reach[rp[k]]) {   // 2 scattered byte reads
                        reach[tid + k * NT] = 1;
                        pend &= ~(1u << k);
                        prog = 1;
                    }
                }
            }
            if (prog) flags[e] = 1;   // plain store, same value from all writers
        }
        __syncthreads();
        if (e >= MAXE - 2 || flags[e] == 0) break;   // broadcast read, uniform
    }

    // ---- output int32 0/1: unpack reach dwords -> int4 coalesced stores ----
    #pragma unroll
    for (int k2 = 0; k2 < (NN / 4) / NT; ++k2) {
        const int j = tid + k2 * NT;               // dword index = nodes 4j..4j+3
        const unsigned w = ((const unsigned*)reach)[j];
        int4 o;
        o.x = (int)( w        & 0xffu);
        o.y = (int)((w >> 8)  & 0xffu);
        o.z = (int)((w >> 16) & 0xffu);
        o.w = (int)((w >> 24) & 0xffu);
        ((int4*)out)[j] = o;
    }
}

extern "C" void kernel_launch(void* const* d_in, const int* in_sizes, int n_in,
                              void* d_out, int out_size, void* d_ws, size_t ws_size,
                              hipStream_t stream) {
    // setup_inputs order: thresholds, rules_left, rules_right, binary_ops, left, right
    const int* left  = (const int*)d_in[4];
    const int* right = (const int*)d_in[5];
    int* out = (int*)d_out;

    dag_reach_kernel<<<1, NT, 0, stream>>>(left, right, out);
}